// Round 1
// 129.645 us; speedup vs baseline: 1.0118x; 1.0118x over previous
//
#include <hip/hip_runtime.h>
#include <stdint.h>

// N=4, C=256, S=16, H*W=1024, 3 layers.
// Algebraic restructure: W_eff[l,n] = (sum_k cw[l][:,k,:]) @ max(m[n],0)  + sparse corrections
// for (n,k,b) where the slice-flag != 1 (expected ~0 such triples for iid-normal adj; handled
// exactly via a bad-list + fp32 delta buffer, so correctness is input-independent).
#define CC   256
#define NB   4
#define HWP  1024
#define EPSV 1e-5f

typedef __attribute__((ext_vector_type(8))) short bf16x8;
typedef __attribute__((ext_vector_type(4))) float f32x4;

__device__ __forceinline__ ushort f2bf(float f) {
    uint32_t u = __float_as_uint(f);
    uint32_t r = (u + 0x7FFFu + ((u >> 16) & 1u)) >> 16;   // RNE
    return (ushort)r;
}

// ---------------------------------------------------------------------------
// Per n: 64x64 tile transpose of adj -> mpT[n][b][a] = bf16(max(m[a,b],0)) (K=a contig),
// and flags for the block's 4 aligned k-slices x 64 b cols; append f!=1 triples to badlist.
__global__ __launch_bounds__(256) void mplusT_flags(const float* __restrict__ adj,
                                                    ushort* __restrict__ mpT,
                                                    unsigned int* __restrict__ count,
                                                    unsigned int* __restrict__ badlist) {
    const int n = blockIdx.y;
    const int at = blockIdx.x >> 2, bt = blockIdx.x & 3;
    const int a0 = at * 64, b0 = bt * 64;
    const float* m = adj + (size_t)n * CC * CC;
    __shared__ float Ms[64][68];
    const int t = threadIdx.x;
    {
        const int ar = t >> 2, bq = (t & 3) * 16;
        const float* src = m + (size_t)(a0 + ar) * CC + b0 + bq;
#pragma unroll
        for (int i = 0; i < 4; ++i)
            *(float4*)&Ms[ar][bq + i * 4] = *(const float4*)(src + i * 4);
    }
    __syncthreads();
    // transpose + relu -> bf16
    {
        const int bl = t >> 2, ac = (t & 3) * 16;
        ushort* dst = mpT + ((size_t)n * CC + b0 + bl) * CC + a0 + ac;
#pragma unroll
        for (int a4 = 0; a4 < 4; ++a4) {
            ushort4 o;
            o.x = f2bf(fmaxf(Ms[ac + a4 * 4 + 0][bl], 0.f));
            o.y = f2bf(fmaxf(Ms[ac + a4 * 4 + 1][bl], 0.f));
            o.z = f2bf(fmaxf(Ms[ac + a4 * 4 + 2][bl], 0.f));
            o.w = f2bf(fmaxf(Ms[ac + a4 * 4 + 3][bl], 0.f));
            *(ushort4*)(dst + a4 * 4) = o;
        }
    }
    // flags: slice k = at*4 + kl (16 a-rows each), col b0+bl
    {
        const int kl = t >> 6, bl = t & 63;
        bool allp = true, anyp = false;
#pragma unroll
        for (int i = 0; i < 16; ++i) {
            bool p = Ms[kl * 16 + i][bl] > 0.0f;
            allp = allp && p;
            anyp = anyp || p;
        }
        const int f = allp ? 2 : (anyp ? 1 : 0);
        if (f != 1) {
            unsigned int pos = atomicAdd(count, 1u);
            const int k = at * 4 + kl;
            badlist[pos] = (unsigned int)((f << 16) | (n << 12) | (k << 8) | (b0 + bl));
        }
    }
}

// ---------------------------------------------------------------------------
// cwS[l][o][a] = bf16( sum_{k=0..15} conv_w[l][o][k*256+a] )   (fp32 accumulate)
__global__ __launch_bounds__(256) void cwsum_kernel(const float* __restrict__ w,
                                                    ushort* __restrict__ cwS) {
    const int idx = (blockIdx.x * 256 + threadIdx.x) * 4;   // over 3*256*256
    const int l = idx >> 16;
    const int o = (idx >> 8) & 255;
    const int a = idx & 255;
    const float* src = w + (size_t)l * 1048576 + (size_t)o * 4096 + a;
    float4 s = {0.f, 0.f, 0.f, 0.f};
#pragma unroll
    for (int k = 0; k < 16; ++k) {
        float4 v = *(const float4*)(src + k * 256);
        s.x += v.x; s.y += v.y; s.z += v.z; s.w += v.w;
    }
    ushort4 ob = {f2bf(s.x), f2bf(s.y), f2bf(s.z), f2bf(s.w)};
    *(ushort4*)(cwS + idx) = ob;
}

// ---------------------------------------------------------------------------
// Sparse exact correction: for each bad (n,k,b):
//   f==0: Wdelta[l,n][o,b] -= sum_a cw[l][o,k*256+a] * max(m[a,b],0)
//   f==2: Wdelta[l,n][o,b] -= sum_a cw[l][o,k*256+a] * max(-m[a,b],0)
// Expected count ~0; grid (48,3), thread = o.
__global__ __launch_bounds__(256) void correction_kernel(const float* __restrict__ adj,
                                                         const float* __restrict__ conv_w,
                                                         const unsigned int* __restrict__ count,
                                                         const unsigned int* __restrict__ badlist,
                                                         float* __restrict__ Wdelta) {
    const int l = blockIdx.y;
    const unsigned int cnt = *count;
    __shared__ float v[256];
    const int t = threadIdx.x;
    for (unsigned int i = blockIdx.x; i < cnt; i += gridDim.x) {
        const unsigned int e = badlist[i];
        const int b = e & 255, k = (e >> 8) & 15, n = (e >> 12) & 3, f = (e >> 16) & 3;
        __syncthreads();
        const float mv = adj[(size_t)n * 65536 + (size_t)t * CC + b];
        v[t] = (f == 0) ? fmaxf(mv, 0.f) : fmaxf(-mv, 0.f);
        __syncthreads();
        const float* cw = conv_w + (size_t)l * 1048576 + (size_t)t * 4096 + k * 256;
        float s = 0.f;
#pragma unroll 8
        for (int a = 0; a < 256; ++a) s += cw[a] * v[a];
        atomicAdd(Wdelta + (((size_t)(l * 4 + n) * 256 + t) * 256 + b), -s);
    }
}

// ---------------------------------------------------------------------------
// Ws[l,n][o][b] = bf16( sc_o * ( cwS[l] @ mpT[n]^T  [+ Wdelta if any corrections] ) )
// Batched 256x256x256 bf16 MFMA GEMM; 64x64 tiles, 4 waves x (2x2) frags; grid (16, 12).
__global__ __launch_bounds__(256) void wbase_mfma(const ushort* __restrict__ cwS,
                                                  const ushort* __restrict__ mpT,
                                                  const float* __restrict__ gamma,
                                                  const float* __restrict__ var,
                                                  const unsigned int* __restrict__ count,
                                                  const float* __restrict__ Wdelta,
                                                  ushort* __restrict__ Ws) {
    const int tile = blockIdx.x;
    const int ln = blockIdx.y;
    const int l = ln >> 2, n = ln & 3;
    const int trow = (tile >> 2) * 64, tcol = (tile & 3) * 64;
    const ushort* A = cwS + (size_t)l * 65536;     // [o][a], a contig
    const ushort* B = mpT + (size_t)n * 65536;     // [b][a], a contig
    __shared__ ushort Al[64][40];
    __shared__ ushort Bl[64][40];
    const int t = threadIdx.x;
    const int wv = t >> 6, L = t & 63;
    const int wr = (wv >> 1) * 32, wc = (wv & 1) * 32;
    const int l16 = L & 15, q = L >> 4;
    const int r0 = t >> 2, kq0 = (t & 3) * 8;
    f32x4 acc[2][2];
#pragma unroll
    for (int i = 0; i < 2; ++i)
#pragma unroll
        for (int j = 0; j < 2; ++j)
            acc[i][j] = (f32x4){0.f, 0.f, 0.f, 0.f};

    for (int kt = 0; kt < 8; ++kt) {
        const int kk = kt * 32;
        int4 av = *(const int4*)(A + (size_t)(trow + r0) * CC + kk + kq0);
        int4 bv = *(const int4*)(B + (size_t)(tcol + r0) * CC + kk + kq0);
        __syncthreads();
        *(int4*)&Al[r0][kq0] = av;
        *(int4*)&Bl[r0][kq0] = bv;
        __syncthreads();
        bf16x8 af[2], bfr[2];
#pragma unroll
        for (int i = 0; i < 2; ++i)
            af[i] = *(const bf16x8*)&Al[wr + i * 16 + l16][q * 8];
#pragma unroll
        for (int j = 0; j < 2; ++j)
            bfr[j] = *(const bf16x8*)&Bl[wc + j * 16 + l16][q * 8];
#pragma unroll
        for (int i = 0; i < 2; ++i)
#pragma unroll
            for (int j = 0; j < 2; ++j)
                acc[i][j] = __builtin_amdgcn_mfma_f32_16x16x32_bf16(af[i], bfr[j], acc[i][j], 0, 0, 0);
    }

    const unsigned int cnt = *count;
    ushort* W = Ws + (size_t)ln * 65536;
    const float* Wd = Wdelta + (size_t)ln * 65536;
#pragma unroll
    for (int i = 0; i < 2; ++i)
#pragma unroll
        for (int j = 0; j < 2; ++j) {
            const int ob = trow + wr + i * 16 + q * 4;   // D row = quad*4 + reg
            const int b  = tcol + wc + j * 16 + l16;     // D col = lane&15
#pragma unroll
            for (int r = 0; r < 4; ++r) {
                const int o = ob + r;
                float a = acc[i][j][r];
                if (cnt) a += Wd[(size_t)o * CC + b];
                const float sc = gamma[l * CC + o] * rsqrtf(var[l * CC + o] + EPSV);
                W[(size_t)o * CC + b] = f2bf(a * sc);
            }
        }
}

// ---------------------------------------------------------------------------
// Fused 3-layer chain. Block owns 16 p-rows x all 256 channels of one n.
// x panel lives in LDS (ping-pong, padded for conflict-free ds_read_b128 A-frags);
// W streamed straight from L2 (1.5 MB total, resident). One barrier per layer.
// Grid (64, 4) = 256 blocks, 4 waves; wave wv owns o-frags wv*4..wv*4+3.
__global__ __launch_bounds__(256) void fused_layers(const float* __restrict__ feats,
                                                    const ushort* __restrict__ Ws,
                                                    const float* __restrict__ conv_b,
                                                    const float* __restrict__ gamma,
                                                    const float* __restrict__ beta,
                                                    const float* __restrict__ mean,
                                                    const float* __restrict__ var,
                                                    float* __restrict__ out) {
    const int n = blockIdx.y;
    const int p0 = blockIdx.x * 16;
    __shared__ ushort xl[2][16][264];   // +8 shorts pad: conflict-free b128 col reads
    const int t = threadIdx.x;
    const int wv = t >> 6, L = t & 63;
    const int l16 = L & 15, q = L >> 4;

    // Load + transpose x0: thread t = channel c, 16 p-values.
    {
        const float* src = feats + ((size_t)n * CC + t) * HWP + p0;
        float v[16];
#pragma unroll
        for (int i = 0; i < 4; ++i)
            *(float4*)&v[i * 4] = *(const float4*)(src + i * 4);
#pragma unroll
        for (int i = 0; i < 16; ++i)
            xl[0][i][t] = f2bf(v[i]);
    }
    __syncthreads();

    int cur = 0;
    for (int l = 0; l < 3; ++l) {
        const ushort* Bw = Ws + (size_t)(l * 4 + n) * 65536;   // [o][b], b contig
        f32x4 acc[4];
#pragma unroll
        for (int jj = 0; jj < 4; ++jj) acc[jj] = (f32x4){0.f, 0.f, 0.f, 0.f};

#pragma unroll
        for (int kt = 0; kt < 8; ++kt) {
            const int kk = kt * 32;
            bf16x8 af = *(const bf16x8*)&xl[cur][l16][kk + q * 8];
#pragma unroll
            for (int jj = 0; jj < 4; ++jj) {
                const int o = (wv * 4 + jj) * 16 + l16;
                bf16x8 bv = *(const bf16x8*)(Bw + (size_t)o * CC + kk + q * 8);
                acc[jj] = __builtin_amdgcn_mfma_f32_16x16x32_bf16(af, bv, acc[jj], 0, 0, 0);
            }
        }

        float* outn = out + (size_t)(l * 4 + n) * CC * HWP;
#pragma unroll
        for (int jj = 0; jj < 4; ++jj) {
            const int o = (wv * 4 + jj) * 16 + l16;
            const float sc = gamma[l * CC + o] * rsqrtf(var[l * CC + o] + EPSV);
            const float b2 = sc * (conv_b[l * CC + o] - mean[l * CC + o]) + beta[l * CC + o];
            const float v0 = fmaxf(acc[jj][0] + b2, 0.f);
            const float v1 = fmaxf(acc[jj][1] + b2, 0.f);
            const float v2 = fmaxf(acc[jj][2] + b2, 0.f);
            const float v3 = fmaxf(acc[jj][3] + b2, 0.f);
            *(float4*)(outn + (size_t)o * HWP + p0 + q * 4) = (float4){v0, v1, v2, v3};
            if (l < 2) {
                xl[cur ^ 1][q * 4 + 0][o] = f2bf(v0);
                xl[cur ^ 1][q * 4 + 1][o] = f2bf(v1);
                xl[cur ^ 1][q * 4 + 2][o] = f2bf(v2);
                xl[cur ^ 1][q * 4 + 3][o] = f2bf(v3);
            }
        }
        __syncthreads();
        cur ^= 1;
    }
}

// ---------------------------------------------------------------------------
extern "C" void kernel_launch(void* const* d_in, const int* in_sizes, int n_in,
                              void* d_out, int out_size, void* d_ws, size_t ws_size,
                              hipStream_t stream) {
    const float* feats  = (const float*)d_in[0];
    const float* adj    = (const float*)d_in[1];
    const float* conv_w = (const float*)d_in[2];
    const float* conv_b = (const float*)d_in[3];
    const float* gamma  = (const float*)d_in[4];
    const float* beta   = (const float*)d_in[5];
    const float* mean   = (const float*)d_in[6];
    const float* var    = (const float*)d_in[7];
    float* out = (float*)d_out;

    // ws layout (bytes):
    //   [0, 3145728)          Wdelta fp32 [12][256][256]
    //   [3145728, +64)        count (uint) + pad
    //   [3145792, +65536)     badlist uint[16384]
    //   [3211328, +393216)    cwS bf16 [3][256][256]
    //   [3604544, +524288)    mpT bf16 [4][256][256]
    //   [4128832, +1572864)   Ws  bf16 [12][256][256]
    char* ws = (char*)d_ws;
    float*        Wdelta  = (float*)ws;
    unsigned int* count   = (unsigned int*)(ws + 3145728);
    unsigned int* badlist = (unsigned int*)(ws + 3145792);
    ushort*       cwS     = (ushort*)(ws + 3211328);
    ushort*       mpT     = (ushort*)(ws + 3604544);
    ushort*       Wsb     = (ushort*)(ws + 4128832);

    hipMemsetAsync(ws, 0, 3145792, stream);   // Wdelta + count

    mplusT_flags<<<dim3(16, NB), 256, 0, stream>>>(adj, mpT, count, badlist);
    cwsum_kernel<<<192, 256, 0, stream>>>(conv_w, cwS);
    correction_kernel<<<dim3(48, 3), 256, 0, stream>>>(adj, conv_w, count, badlist, Wdelta);
    wbase_mfma<<<dim3(16, 12), 256, 0, stream>>>(cwS, mpT, gamma, var, count, Wdelta, Wsb);
    fused_layers<<<dim3(64, NB), 256, 0, stream>>>(feats, Wsb, conv_b, gamma, beta, mean, var, out);
}